// Round 1
// baseline (451.615 us; speedup 1.0000x reference)
//
#include <hip/hip_runtime.h>
#include <math.h>

#define NSTR 4
#define DEMB 1024
#define KDIM 4096          // NSTR * DEMB
#define CTOT 24            // N*N + 2N coefficient rows
#define RSTR 25            // 24 raw + 1 sumsq
#define NTOK 8192          // B*T
#define TOK_PER_BLK 8
#define SLICES 32          // k-slices per token
#define ITERS 32           // KDIM / (SLICES*4)

// ---------------- Kernel 1: raw[c] = x . W[c,:]  and sumsq(x), per token ----
// 256 thr = 8 tokens x 32 k-slices. W addresses repeat every 32 lanes ->
// coalesced 512B W reads; per-block W traffic served from L2 (W = 393 KB).
__global__ __launch_bounds__(256) void k_raw(
    const float* __restrict__ state,
    const float* __restrict__ W,
    float* __restrict__ raw_g)
{
    const int tid = threadIdx.x;
    const int j  = tid & (SLICES - 1);   // k-slice
    const int tl = tid >> 5;             // token within block
    const int token = blockIdx.x * TOK_PER_BLK + tl;
    const float* xp = state + (size_t)token * KDIM;

    float acc[CTOT];
#pragma unroll
    for (int c = 0; c < CTOT; ++c) acc[c] = 0.f;
    float ss = 0.f;

#pragma unroll 2
    for (int i = 0; i < ITERS; ++i) {
        const int k = (j << 2) + (i << 7);
        const float4 x = *(const float4*)(xp + k);
        ss += x.x*x.x + x.y*x.y + x.z*x.z + x.w*x.w;
        const float* wp = W + k;
#pragma unroll
        for (int c = 0; c < CTOT; ++c) {
            const float4 w = *(const float4*)(wp + c * KDIM);
            acc[c] += x.x*w.x + x.y*w.y + x.z*w.z + x.w*w.w;
        }
    }

    __shared__ float red[256][RSTR];
#pragma unroll
    for (int c = 0; c < CTOT; ++c) red[tid][c] = acc[c];
    red[tid][CTOT] = ss;
    __syncthreads();

    if (tid < TOK_PER_BLK * RSTR) {      // 200 outputs
        const int t = tid / RSTR;
        const int c = tid - t * RSTR;
        float s = 0.f;
#pragma unroll
        for (int jj = 0; jj < SLICES; ++jj) s += red[t * SLICES + jj][c];
        raw_g[(size_t)(blockIdx.x * TOK_PER_BLK + t) * RSTR + c] = s;
    }
}

// ---------------- Kernel 2: gates + sinkhorn + outputs, one block per token --
__global__ __launch_bounds__(256) void k_out(
    const float* __restrict__ state,
    const float* __restrict__ residual,
    const float* __restrict__ alpha,
    const float* __restrict__ bias,
    const float* __restrict__ raw_g,
    float* __restrict__ out)
{
    const int token = blockIdx.x;
    const int tid = threadIdx.x;

    __shared__ float s_raw[RSTR];
    __shared__ float s_h[24];            // h_pre[0..3], h_post[4..7], h_res[8..23]

    if (tid < RSTR) s_raw[tid] = raw_g[(size_t)token * RSTR + tid];
    __syncthreads();

    if (tid == 0) {
        // rmsnorm scale: raw was computed on unnormalized x; raw_norm = raw*scale
        const float scale = rsqrtf(s_raw[CTOT] * (1.f / KDIM) + 1.1920928955078125e-07f);
        const float a0 = alpha[0], a1 = alpha[1], a2 = alpha[2];
        float h[8];
#pragma unroll
        for (int n = 0; n < 4; ++n) {
            float x = a0 * (s_raw[n] * scale) + bias[n];
            h[n] = 1.f / (1.f + __expf(-x));
        }
#pragma unroll
        for (int n = 0; n < 4; ++n) {
            float x = a1 * (s_raw[4 + n] * scale) + bias[4 + n];
            h[4 + n] = 2.f / (1.f + __expf(-x));
        }
        float m[16];
#pragma unroll
        for (int e = 0; e < 16; ++e) {
            float x = a2 * (s_raw[8 + e] * scale) + bias[8 + e];
            x = fminf(fmaxf(x, -20.f), 20.f);
            m[e] = __expf(x);
        }
#pragma unroll
        for (int it = 0; it < 10; ++it) {
            // normalize columns (sum over axis -2 == over rows i)
#pragma unroll
            for (int jj = 0; jj < 4; ++jj) {
                float cs = m[jj] + m[4 + jj] + m[8 + jj] + m[12 + jj];
                float inv = __builtin_amdgcn_rcpf(fmaxf(cs, 1e-12f));
                m[jj] *= inv; m[4 + jj] *= inv; m[8 + jj] *= inv; m[12 + jj] *= inv;
            }
            // normalize rows (axis -1)
#pragma unroll
            for (int ii = 0; ii < 4; ++ii) {
                float rs = m[4*ii] + m[4*ii + 1] + m[4*ii + 2] + m[4*ii + 3];
                float inv = __builtin_amdgcn_rcpf(fmaxf(rs, 1e-12f));
                m[4*ii] *= inv; m[4*ii + 1] *= inv; m[4*ii + 2] *= inv; m[4*ii + 3] *= inv;
            }
        }
#pragma unroll
        for (int n = 0; n < 8; ++n) s_h[n] = h[n];
#pragma unroll
        for (int e = 0; e < 16; ++e) s_h[8 + e] = m[e];
    }
    __syncthreads();

    // Phase B: each thread handles 4 consecutive dims (float4), coalesced.
    const float4* sp = (const float4*)(state + (size_t)token * KDIM);
    const float4 x0 = sp[tid];
    const float4 x1 = sp[256 + tid];
    const float4 x2 = sp[512 + tid];
    const float4 x3 = sp[768 + tid];
    const float4 r  = ((const float4*)(residual + (size_t)token * DEMB))[tid];

    const float hp0 = s_h[0], hp1 = s_h[1], hp2 = s_h[2], hp3 = s_h[3];
    float4 pre;
    pre.x = hp0*x0.x + hp1*x1.x + hp2*x2.x + hp3*x3.x;
    pre.y = hp0*x0.y + hp1*x1.y + hp2*x2.y + hp3*x3.y;
    pre.z = hp0*x0.z + hp1*x1.z + hp2*x2.z + hp3*x3.z;
    pre.w = hp0*x0.w + hp1*x1.w + hp2*x2.w + hp3*x3.w;
    ((float4*)(out + (size_t)token * DEMB))[tid] = pre;

    float4* ns = (float4*)(out + (size_t)NTOK * DEMB + (size_t)token * KDIM);
#pragma unroll
    for (int i2 = 0; i2 < 4; ++i2) {
        const float w0 = s_h[8 + 4*i2 + 0];
        const float w1 = s_h[8 + 4*i2 + 1];
        const float w2 = s_h[8 + 4*i2 + 2];
        const float w3 = s_h[8 + 4*i2 + 3];
        const float hp = s_h[4 + i2];
        float4 o;
        o.x = w0*x0.x + w1*x1.x + w2*x2.x + w3*x3.x + hp*r.x;
        o.y = w0*x0.y + w1*x1.y + w2*x2.y + w3*x3.y + hp*r.y;
        o.z = w0*x0.z + w1*x1.z + w2*x2.z + w3*x3.z + hp*r.z;
        o.w = w0*x0.w + w1*x1.w + w2*x2.w + w3*x3.w + hp*r.w;
        ns[i2 * 256 + tid] = o;
    }
}

extern "C" void kernel_launch(void* const* d_in, const int* in_sizes, int n_in,
                              void* d_out, int out_size, void* d_ws, size_t ws_size,
                              hipStream_t stream) {
    const float* state    = (const float*)d_in[0];
    const float* residual = (const float*)d_in[1];
    const float* W        = (const float*)d_in[2];
    const float* alpha    = (const float*)d_in[3];
    const float* bias     = (const float*)d_in[4];
    float* out   = (float*)d_out;
    float* raw_g = (float*)d_ws;   // NTOK * 25 floats = 820 KB

    hipLaunchKernelGGL(k_raw, dim3(NTOK / TOK_PER_BLK), dim3(256), 0, stream,
                       state, W, raw_g);
    hipLaunchKernelGGL(k_out, dim3(NTOK), dim3(256), 0, stream,
                       state, residual, alpha, bias, raw_g, out);
}

// Round 3
// 321.423 us; speedup vs baseline: 1.4050x; 1.4050x over previous
//
#include <hip/hip_runtime.h>
#include <hip/hip_bf16.h>
#include <math.h>

#define NSTR 4
#define DEMB 1024
#define KDIM 4096
#define CTOT 24
#define NTOK 8192
#define EPSF 1.1920928955078125e-07f

typedef __attribute__((ext_vector_type(8))) short short8;
typedef __attribute__((ext_vector_type(4))) float f32x4;

__device__ __forceinline__ short8 pack8(float4 a, float4 b) {
    union { short8 s; __hip_bfloat162 h[4]; } u;
    u.h[0] = __float22bfloat162_rn(float2{a.x, a.y});
    u.h[1] = __float22bfloat162_rn(float2{a.z, a.w});
    u.h[2] = __float22bfloat162_rn(float2{b.x, b.y});
    u.h[3] = __float22bfloat162_rn(float2{b.z, b.w});
    return u.s;
}

// ---------- Kernel 1: raw[c][t] = x_t . W[c,:], ss[t], via bf16 MFMA --------
// 512 blocks x 16 tokens. 4 waves split K (1024 each); LDS reduction.
// A-frag: A[m=lane&15][k=q*8+j]  B-frag: B[k=q*8+j][n=lane&15]
// D: row(token)=q*4+reg, col(c)=lane&15.
__global__ __launch_bounds__(256, 2) void k_raw(
    const float* __restrict__ state,
    const float* __restrict__ W,
    float* __restrict__ raw_g)
{
    const int tid = threadIdx.x;
    const int w = tid >> 6, lane = tid & 63, q = lane >> 4, mn = lane & 15;
    const int tok0 = blockIdx.x * 16;
    const int k0 = w * 1024 + q * 8;

    const float* Ap  = state + (size_t)(tok0 + mn) * KDIM + k0;
    const float* Bp0 = W + (size_t)mn * KDIM + k0;
    int r1 = 16 + mn; if (r1 > 23) r1 = 23;     // clamp: cols 24..31 unused
    const float* Bp1 = W + (size_t)r1 * KDIM + k0;

    f32x4 acc0 = {0.f, 0.f, 0.f, 0.f};
    f32x4 acc1 = {0.f, 0.f, 0.f, 0.f};
    float ss = 0.f;

#pragma unroll 2
    for (int s = 0; s < 32; ++s) {
        const int off = s * 32;
        const float4 a0  = *(const float4*)(Ap + off);
        const float4 a1  = *(const float4*)(Ap + off + 4);
        const float4 b00 = *(const float4*)(Bp0 + off);
        const float4 b01 = *(const float4*)(Bp0 + off + 4);
        const float4 b10 = *(const float4*)(Bp1 + off);
        const float4 b11 = *(const float4*)(Bp1 + off + 4);
        ss += a0.x*a0.x + a0.y*a0.y + a0.z*a0.z + a0.w*a0.w
            + a1.x*a1.x + a1.y*a1.y + a1.z*a1.z + a1.w*a1.w;
        const short8 af  = pack8(a0, a1);
        const short8 bf0 = pack8(b00, b01);
        const short8 bf1 = pack8(b10, b11);
        acc0 = __builtin_amdgcn_mfma_f32_16x16x32_bf16(af, bf0, acc0, 0, 0, 0);
        acc1 = __builtin_amdgcn_mfma_f32_16x16x32_bf16(af, bf1, acc1, 0, 0, 0);
    }

    __shared__ float part[4][16][28];   // [wave][token][c] (+pad)
    __shared__ float ssb[4][4][16];     // [wave][quad][token]
#pragma unroll
    for (int r = 0; r < 4; ++r) part[w][q * 4 + r][mn] = acc0[r];
    if (mn < 8) {
#pragma unroll
        for (int r = 0; r < 4; ++r) part[w][q * 4 + r][16 + mn] = acc1[r];
    }
    ssb[w][q][mn] = ss;
    __syncthreads();

    // 16 tokens x 25 outputs = 400 > 256 threads: strided loop (R2 bugfix)
    for (int idx = tid; idx < 16 * 25; idx += 256) {
        const int t = idx / 25;
        const int c = idx - t * 25;
        if (c < CTOT) {
            const float v = part[0][t][c] + part[1][t][c] + part[2][t][c] + part[3][t][c];
            raw_g[(size_t)c * NTOK + tok0 + t] = v;      // SoA: coalesced k_gate read
        } else {
            float v = 0.f;
#pragma unroll
            for (int ww = 0; ww < 4; ++ww)
#pragma unroll
                for (int qq = 0; qq < 4; ++qq) v += ssb[ww][qq][t];
            raw_g[(size_t)CTOT * NTOK + tok0 + t] = v;
        }
    }
}

// ---------- Kernel 2: gates + sinkhorn, ONE THREAD PER TOKEN ----------------
__global__ __launch_bounds__(256) void k_gate(
    const float* __restrict__ raw_g,
    const float* __restrict__ alpha,
    const float* __restrict__ bias,
    float* __restrict__ h_g)
{
    const int t = blockIdx.x * 256 + threadIdx.x;   // exactly NTOK threads
    float r[25];
#pragma unroll
    for (int c = 0; c < 25; ++c) r[c] = raw_g[(size_t)c * NTOK + t];

    const float scale = rsqrtf(r[24] * (1.f / KDIM) + EPSF);
    const float a0 = alpha[0], a1 = alpha[1], a2 = alpha[2];
    float h[24];
#pragma unroll
    for (int n = 0; n < 4; ++n) {
        float x = a0 * (r[n] * scale) + bias[n];
        h[n] = 1.f / (1.f + __expf(-x));
    }
#pragma unroll
    for (int n = 0; n < 4; ++n) {
        float x = a1 * (r[4 + n] * scale) + bias[4 + n];
        h[4 + n] = 2.f / (1.f + __expf(-x));
    }
    float m[16];
#pragma unroll
    for (int e = 0; e < 16; ++e) {
        float x = a2 * (r[8 + e] * scale) + bias[8 + e];
        x = fminf(fmaxf(x, -20.f), 20.f);
        m[e] = __expf(x);
    }
#pragma unroll
    for (int it = 0; it < 10; ++it) {
#pragma unroll
        for (int jj = 0; jj < 4; ++jj) {
            float cs = m[jj] + m[4 + jj] + m[8 + jj] + m[12 + jj];
            float inv = __builtin_amdgcn_rcpf(fmaxf(cs, 1e-12f));
            m[jj] *= inv; m[4 + jj] *= inv; m[8 + jj] *= inv; m[12 + jj] *= inv;
        }
#pragma unroll
        for (int ii = 0; ii < 4; ++ii) {
            float rs = m[4*ii] + m[4*ii+1] + m[4*ii+2] + m[4*ii+3];
            float inv = __builtin_amdgcn_rcpf(fmaxf(rs, 1e-12f));
            m[4*ii] *= inv; m[4*ii+1] *= inv; m[4*ii+2] *= inv; m[4*ii+3] *= inv;
        }
    }
#pragma unroll
    for (int e = 0; e < 16; ++e) h[8 + e] = m[e];

    float* hp = h_g + (size_t)t * 24;               // AoS: uniform k_mix read
#pragma unroll
    for (int c = 0; c < 24; ++c) hp[c] = h[c];
}

// ---------- Kernel 3: pure streaming mix; no LDS, no barriers ---------------
__global__ __launch_bounds__(256) void k_mix(
    const float* __restrict__ state,
    const float* __restrict__ residual,
    const float* __restrict__ h_g,
    float* __restrict__ out)
{
    const int token = blockIdx.x;
    const int tid = threadIdx.x;
    const float* hh = h_g + (size_t)token * 24;     // wave-uniform -> s_loads

    const float4* sp = (const float4*)(state + (size_t)token * KDIM);
    const float4 x0 = sp[tid];
    const float4 x1 = sp[256 + tid];
    const float4 x2 = sp[512 + tid];
    const float4 x3 = sp[768 + tid];
    const float4 rr = ((const float4*)(residual + (size_t)token * DEMB))[tid];

    const float hp0 = hh[0], hp1 = hh[1], hp2 = hh[2], hp3 = hh[3];
    float4 pre;
    pre.x = hp0*x0.x + hp1*x1.x + hp2*x2.x + hp3*x3.x;
    pre.y = hp0*x0.y + hp1*x1.y + hp2*x2.y + hp3*x3.y;
    pre.z = hp0*x0.z + hp1*x1.z + hp2*x2.z + hp3*x3.z;
    pre.w = hp0*x0.w + hp1*x1.w + hp2*x2.w + hp3*x3.w;
    ((float4*)(out + (size_t)token * DEMB))[tid] = pre;

    float4* ns = (float4*)(out + (size_t)NTOK * DEMB + (size_t)token * KDIM);
#pragma unroll
    for (int i2 = 0; i2 < 4; ++i2) {
        const float w0 = hh[8 + 4*i2 + 0];
        const float w1 = hh[8 + 4*i2 + 1];
        const float w2 = hh[8 + 4*i2 + 2];
        const float w3 = hh[8 + 4*i2 + 3];
        const float hp = hh[4 + i2];
        float4 o;
        o.x = w0*x0.x + w1*x1.x + w2*x2.x + w3*x3.x + hp*rr.x;
        o.y = w0*x0.y + w1*x1.y + w2*x2.y + w3*x3.y + hp*rr.y;
        o.z = w0*x0.z + w1*x1.z + w2*x2.z + w3*x3.z + hp*rr.z;
        o.w = w0*x0.w + w1*x1.w + w2*x2.w + w3*x3.w + hp*rr.w;
        ns[i2 * 256 + tid] = o;
    }
}

extern "C" void kernel_launch(void* const* d_in, const int* in_sizes, int n_in,
                              void* d_out, int out_size, void* d_ws, size_t ws_size,
                              hipStream_t stream) {
    const float* state    = (const float*)d_in[0];
    const float* residual = (const float*)d_in[1];
    const float* W        = (const float*)d_in[2];
    const float* alpha    = (const float*)d_in[3];
    const float* bias     = (const float*)d_in[4];
    float* out   = (float*)d_out;
    float* raw_g = (float*)d_ws;                       // 25*NTOK floats
    float* h_g   = raw_g + (size_t)25 * NTOK;          // 24*NTOK floats

    hipLaunchKernelGGL(k_raw,  dim3(NTOK / 16), dim3(256), 0, stream, state, W, raw_g);
    hipLaunchKernelGGL(k_gate, dim3(NTOK / 256), dim3(256), 0, stream, raw_g, alpha, bias, h_g);
    hipLaunchKernelGGL(k_mix,  dim3(NTOK), dim3(256), 0, stream, state, residual, h_g, out);
}